// Round 1
// baseline (257.571 us; speedup 1.0000x reference)
//
#include <hip/hip_runtime.h>
#include <hip/hip_fp16.h>
#include <cstdint>

#define IN_U 2048
#define OUT_U 2048
#define NH 10
#define BATCH 4096

typedef _Float16 f16;
typedef _Float16 f16x8 __attribute__((ext_vector_type(8)));
typedef float f32x4 __attribute__((ext_vector_type(4)));

// ---------------- kernel 1a: A[i][h] = sum_k W[i][k] * W1[k][h] ----------------
// one wave per row i; coalesced float4 row reads; W1-top (80KB) L2-resident.
__global__ __launch_bounds__(256) void k_rowA(const float* __restrict__ W,
                                              const float* __restrict__ W1,
                                              float* __restrict__ A) {
  int lane = threadIdx.x & 63;
  int i = blockIdx.x * 4 + (threadIdx.x >> 6);
  float acc[NH];
#pragma unroll
  for (int h = 0; h < NH; ++h) acc[h] = 0.f;
  const float* wrow = W + (size_t)i * OUT_U;
  for (int k0 = lane * 4; k0 < OUT_U; k0 += 256) {
    float4 w4 = *(const float4*)(wrow + k0);
#pragma unroll
    for (int e = 0; e < 4; ++e) {
      float wv = (&w4.x)[e];
      const float* w1r = W1 + (size_t)(k0 + e) * NH;
#pragma unroll
      for (int h = 0; h < NH; ++h) acc[h] = fmaf(wv, w1r[h], acc[h]);
    }
  }
#pragma unroll
  for (int off = 32; off > 0; off >>= 1) {
#pragma unroll
    for (int h = 0; h < NH; ++h) acc[h] += __shfl_xor(acc[h], off, 64);
  }
  if (lane == 0) {
#pragma unroll
    for (int h = 0; h < NH; ++h) A[(size_t)i * NH + h] = acc[h];
  }
}

// ---------------- kernel 1b: B[j][h] = sum_k W[k][j] * W1[out_u+k][h] ----------------
// lane -> column j (coalesced W reads); 8-way k-split within block + LDS reduce.
__global__ __launch_bounds__(512) void k_colB(const float* __restrict__ W,
                                              const float* __restrict__ W1,
                                              float* __restrict__ B) {
  __shared__ float red[8][64][NH];
  int tid = threadIdx.x;
  int jl = tid & 63;
  int kq = tid >> 6;  // 0..7
  int j = blockIdx.x * 64 + jl;
  float acc[NH];
#pragma unroll
  for (int h = 0; h < NH; ++h) acc[h] = 0.f;
  const float* w1b = W1 + (size_t)OUT_U * NH;
#pragma unroll 4
  for (int k = kq * 256; k < kq * 256 + 256; ++k) {
    float wv = W[(size_t)k * OUT_U + j];
    const float* w1r = w1b + (size_t)k * NH;
#pragma unroll
    for (int h = 0; h < NH; ++h) acc[h] = fmaf(wv, w1r[h], acc[h]);
  }
#pragma unroll
  for (int h = 0; h < NH; ++h) red[kq][jl][h] = acc[h];
  __syncthreads();
  if (kq == 0) {
#pragma unroll
    for (int h = 0; h < NH; ++h) {
      float s = 0.f;
#pragma unroll
      for (int q = 0; q < 8; ++q) s += red[q][jl][h];
      B[(size_t)j * NH + h] = s;
    }
  }
}

// ---------------- kernel 2: W_new^T (f16)  ----------------
// 64x64 (i,j) tile; W tile staged transposed in LDS (pad 65 -> conflict-free);
// W2 held in registers (static indices only, rule #20); store WnT[j][i] coalesced.
__global__ __launch_bounds__(256) void k_wnew(const float* __restrict__ W,
                                              const float* __restrict__ A,
                                              const float* __restrict__ Bv,
                                              const float* __restrict__ b1,
                                              const float* __restrict__ W2,
                                              const float* __restrict__ b2,
                                              const float* __restrict__ W3,
                                              const float* __restrict__ b3,
                                              f16* __restrict__ WnT) {
  __shared__ float Wt[64 * 65];
  __shared__ float As[64 * NH];
  __shared__ float Bs[64 * NH];
  int tid = threadIdx.x;
  int i0 = blockIdx.x * 64, j0 = blockIdx.y * 64;
#pragma unroll
  for (int it = 0; it < 16; ++it) {
    int idx = it * 256 + tid;
    int r = idx >> 6, c = idx & 63;
    Wt[c * 65 + r] = W[(size_t)(i0 + r) * OUT_U + j0 + c];  // read coalesced, write transposed
  }
  for (int v = tid; v < 64 * NH; v += 256) {
    As[v] = A[(size_t)i0 * NH + v];
    Bs[v] = Bv[(size_t)j0 * NH + v];
  }
  __syncthreads();
  float w2r[NH * NH], w3r[NH], b1r[NH], b2r[NH];
#pragma unroll
  for (int p = 0; p < NH * NH; ++p) w2r[p] = W2[p];
#pragma unroll
  for (int h = 0; h < NH; ++h) { w3r[h] = W3[h]; b1r[h] = b1[h]; b2r[h] = b2[h]; }
  float b3v = b3[0];
  int lane = tid & 63, w = tid >> 6;
  float ar[NH];
#pragma unroll
  for (int h = 0; h < NH; ++h) ar[h] = As[lane * NH + h] + b1r[h];
  for (int jj = 0; jj < 16; ++jj) {
    int jl = w * 16 + jj;
    float h1[NH];
#pragma unroll
    for (int p = 0; p < NH; ++p) h1[p] = fmaxf(ar[p] + Bs[jl * NH + p], 0.f);
    float d = b3v;
#pragma unroll
    for (int q = 0; q < NH; ++q) {
      float s = b2r[q];
#pragma unroll
      for (int p = 0; p < NH; ++p) s = fmaf(h1[p], w2r[p * NH + q], s);
      d = fmaf(fmaxf(s, 0.f), w3r[q], d);
    }
    float wn = Wt[jl * 65 + lane] + d;
    WnT[(size_t)(j0 + jl) * IN_U + i0 + lane] = (f16)wn;
  }
}

// ---------------- kernel 3: X (f32) -> X16 (f16) ----------------
__global__ __launch_bounds__(256) void k_castX(const float* __restrict__ X,
                                               f16* __restrict__ X16) {
  int idx = blockIdx.x * 256 + threadIdx.x;
  const float4* src = (const float4*)X;
  float4 a = src[idx * 2];
  float4 b = src[idx * 2 + 1];
  f16x8 o;
  o[0] = (f16)a.x; o[1] = (f16)a.y; o[2] = (f16)a.z; o[3] = (f16)a.w;
  o[4] = (f16)b.x; o[5] = (f16)b.y; o[6] = (f16)b.z; o[7] = (f16)b.w;
  *((f16x8*)X16 + idx) = o;
}

// ---------------- kernel 4: logits = X16 @ WnT^T  (m97 structure) ----------------
__device__ __forceinline__ void gld_lds16(const void* g, void* l) {
  __builtin_amdgcn_global_load_lds((const __attribute__((address_space(1))) uint32_t*)g,
                                   (__attribute__((address_space(3))) uint32_t*)l, 16, 0, 0);
}

__global__ __launch_bounds__(256) void k_gemm(const f16* __restrict__ Am,
                                              const f16* __restrict__ Bt,
                                              float* __restrict__ C) {
  constexpr int K = IN_U;   // 2048
  constexpr int N = OUT_U;  // 2048
  __shared__ f16 Asl[128 * 32];
  __shared__ f16 Bsl[128 * 32];
  int tid = threadIdx.x;
  int lane = tid & 63;
  int w = tid >> 6;
  int wr = w >> 1, wc = w & 1;
  int bn = blockIdx.x, bm = blockIdx.y;

  // staging: linear LDS image [row][k], 16B/lane, wave-uniform LDS base (m104 rule)
  int srow = w * 16 + (lane >> 2);
  int scol = (lane & 3) * 8;
  const f16* srcA0 = Am + (size_t)(bm * 128 + srow) * K + scol;
  const f16* srcA1 = srcA0 + (size_t)64 * K;
  const f16* srcB0 = Bt + (size_t)(bn * 128 + srow) * K + scol;
  const f16* srcB1 = srcB0 + (size_t)64 * K;
  f16* dstA0 = Asl + w * 512;
  f16* dstA1 = Asl + 2048 + w * 512;
  f16* dstB0 = Bsl + w * 512;
  f16* dstB1 = Bsl + 2048 + w * 512;

  f32x4 acc[4][4];
#pragma unroll
  for (int m = 0; m < 4; ++m)
#pragma unroll
    for (int n = 0; n < 4; ++n) acc[m][n] = (f32x4){0.f, 0.f, 0.f, 0.f};

  const f16* ardA = Asl + (size_t)(wr * 64 + (lane & 15)) * 32 + (lane >> 4) * 8;
  const f16* brdB = Bsl + (size_t)(wc * 64 + (lane & 15)) * 32 + (lane >> 4) * 8;

  for (int kt = 0; kt < K / 32; ++kt) {
    gld_lds16(srcA0, dstA0);
    gld_lds16(srcA1, dstA1);
    gld_lds16(srcB0, dstB0);
    gld_lds16(srcB1, dstB1);
    srcA0 += 32; srcA1 += 32; srcB0 += 32; srcB1 += 32;
    __syncthreads();  // compiler drains vmcnt before barrier -> LDS tile valid
    f16x8 af[4], bf[4];
#pragma unroll
    for (int m = 0; m < 4; ++m) af[m] = *(const f16x8*)(ardA + m * 16 * 32);
#pragma unroll
    for (int n = 0; n < 4; ++n) bf[n] = *(const f16x8*)(brdB + n * 16 * 32);
#pragma unroll
    for (int m = 0; m < 4; ++m)
#pragma unroll
      for (int n = 0; n < 4; ++n)
        acc[m][n] = __builtin_amdgcn_mfma_f32_16x16x32_f16(af[m], bf[n], acc[m][n], 0, 0, 0);
    __syncthreads();
  }

  // D layout: col = lane&15, row = (lane>>4)*4 + v  (m89/m91 verified)
  int r0 = bm * 128 + wr * 64 + (lane >> 4) * 4;
  int c0 = bn * 128 + wc * 64 + (lane & 15);
#pragma unroll
  for (int m = 0; m < 4; ++m)
#pragma unroll
    for (int n = 0; n < 4; ++n)
#pragma unroll
      for (int v = 0; v < 4; ++v)
        C[(size_t)(r0 + m * 16 + v) * N + c0 + n * 16] = acc[m][n][v];
}

// ---------------- kernel 5: row softmax in-place on logits ----------------
__global__ __launch_bounds__(256) void k_softmax(float* __restrict__ L) {
  __shared__ float sred[4];
  int tid = threadIdx.x;
  int lane = tid & 63, w = tid >> 6;
  float4* Lr = (float4*)(L + (size_t)blockIdx.x * OUT_U);
  float4 v0 = Lr[tid];
  float4 v1 = Lr[tid + 256];
  float m = fmaxf(fmaxf(fmaxf(v0.x, v0.y), fmaxf(v0.z, v0.w)),
                  fmaxf(fmaxf(v1.x, v1.y), fmaxf(v1.z, v1.w)));
#pragma unroll
  for (int off = 32; off > 0; off >>= 1) m = fmaxf(m, __shfl_xor(m, off, 64));
  if (lane == 0) sred[w] = m;
  __syncthreads();
  m = fmaxf(fmaxf(sred[0], sred[1]), fmaxf(sred[2], sred[3]));
  __syncthreads();  // sred reused for sum
  v0.x = __expf(v0.x - m); v0.y = __expf(v0.y - m);
  v0.z = __expf(v0.z - m); v0.w = __expf(v0.w - m);
  v1.x = __expf(v1.x - m); v1.y = __expf(v1.y - m);
  v1.z = __expf(v1.z - m); v1.w = __expf(v1.w - m);
  float s = v0.x + v0.y + v0.z + v0.w + v1.x + v1.y + v1.z + v1.w;
#pragma unroll
  for (int off = 32; off > 0; off >>= 1) s += __shfl_xor(s, off, 64);
  if (lane == 0) sred[w] = s;
  __syncthreads();
  s = sred[0] + sred[1] + sred[2] + sred[3];
  float inv = 1.f / s;
  v0.x *= inv; v0.y *= inv; v0.z *= inv; v0.w *= inv;
  v1.x *= inv; v1.y *= inv; v1.z *= inv; v1.w *= inv;
  Lr[tid] = v0;
  Lr[tid + 256] = v1;
}

extern "C" void kernel_launch(void* const* d_in, const int* in_sizes, int n_in,
                              void* d_out, int out_size, void* d_ws, size_t ws_size,
                              hipStream_t stream) {
  const float* X  = (const float*)d_in[0];
  const float* W  = (const float*)d_in[1];
  const float* W1 = (const float*)d_in[2];
  const float* b1 = (const float*)d_in[3];
  const float* W2 = (const float*)d_in[4];
  const float* b2 = (const float*)d_in[5];
  const float* W3 = (const float*)d_in[6];
  const float* b3 = (const float*)d_in[7];
  float* out = (float*)d_out;

  uint8_t* ws = (uint8_t*)d_ws;
  float* A   = (float*)ws;                          // 2048*10*4   = 81,920 B
  float* B   = (float*)(ws + 81920);                // 81,920 B
  f16*   X16 = (f16*)(ws + 163840);                 // 4096*2048*2 = 16,777,216 B
  f16*   WnT = (f16*)(ws + 163840 + 16777216);      // 2048*2048*2 = 8,388,608 B
  // total ws use ~25.3 MB; logits live in d_out (f32), softmax runs in-place.

  hipLaunchKernelGGL(k_rowA, dim3(512), dim3(256), 0, stream, W, W1, A);
  hipLaunchKernelGGL(k_colB, dim3(32), dim3(512), 0, stream, W, W1, B);
  hipLaunchKernelGGL(k_castX, dim3(4096), dim3(256), 0, stream, X, X16);
  hipLaunchKernelGGL(k_wnew, dim3(32, 32), dim3(256), 0, stream, W, A, B, b1, W2, b2, W3, b3, WnT);
  hipLaunchKernelGGL(k_gemm, dim3(16, 32), dim3(256), 0, stream, X16, WnT, out);
  hipLaunchKernelGGL(k_softmax, dim3(4096), dim3(256), 0, stream, out);
}

// Round 2
// 230.660 us; speedup vs baseline: 1.1167x; 1.1167x over previous
//
#include <hip/hip_runtime.h>
#include <hip/hip_fp16.h>
#include <cstdint>

#define IN_U 2048
#define OUT_U 2048
#define NH 10
#define BATCH 4096

typedef _Float16 f16;
typedef _Float16 f16x8 __attribute__((ext_vector_type(8)));
typedef float f32x4 __attribute__((ext_vector_type(4)));

// ================= k_prep: fused rowA | colB-partials | castX =================
// blocks [0,512): A[i][h] = sum_k W[i][k]*W1[k][h]          (one wave per row)
// blocks [512,768): Bp[kc][j][h] partial over k-chunk kc     (full-GPU k-split)
// blocks [768,4864): X (f32) -> X16 (f16)
__global__ __launch_bounds__(256) void k_prep(const float* __restrict__ W,
                                              const float* __restrict__ W1,
                                              const float* __restrict__ X,
                                              float* __restrict__ A,
                                              float* __restrict__ Bp,
                                              f16* __restrict__ X16) {
  __shared__ float red[4 * 64 * NH];  // colB reduce buffer (10 KB)
  int blk = blockIdx.x;
  int tid = threadIdx.x;
  int lane = tid & 63;
  int wv = tid >> 6;

  if (blk < 512) {
    // ---- rowA: i = blk*4 + wv ----
    int i = blk * 4 + wv;
    float acc[NH];
#pragma unroll
    for (int h = 0; h < NH; ++h) acc[h] = 0.f;
    const float* wrow = W + (size_t)i * OUT_U;
    for (int k0 = lane * 4; k0 < OUT_U; k0 += 256) {
      float4 w4 = *(const float4*)(wrow + k0);
#pragma unroll
      for (int e = 0; e < 4; ++e) {
        float wval = (&w4.x)[e];
        const float* w1r = W1 + (size_t)(k0 + e) * NH;
#pragma unroll
        for (int h = 0; h < NH; ++h) acc[h] = fmaf(wval, w1r[h], acc[h]);
      }
    }
#pragma unroll
    for (int off = 32; off > 0; off >>= 1) {
#pragma unroll
      for (int h = 0; h < NH; ++h) acc[h] += __shfl_xor(acc[h], off, 64);
    }
    if (lane == 0) {
#pragma unroll
      for (int h = 0; h < NH; ++h) A[(size_t)i * NH + h] = acc[h];
    }
  } else if (blk < 768) {
    // ---- colB partial: block (jt,kc); wave wv covers 64 k's ----
    int pb = blk - 512;
    int jt = pb & 31, kc = pb >> 5;
    int j = jt * 64 + lane;
    float acc[NH];
#pragma unroll
    for (int h = 0; h < NH; ++h) acc[h] = 0.f;
    const float* w1b = W1 + (size_t)OUT_U * NH;
    int k0 = kc * 256 + wv * 64;
#pragma unroll 4
    for (int k = k0; k < k0 + 64; ++k) {
      float wval = W[(size_t)k * OUT_U + j];
      const float* w1r = w1b + (size_t)k * NH;
#pragma unroll
      for (int h = 0; h < NH; ++h) acc[h] = fmaf(wval, w1r[h], acc[h]);
    }
#pragma unroll
    for (int h = 0; h < NH; ++h) red[wv * 640 + lane * NH + h] = acc[h];
    __syncthreads();
    for (int v = tid; v < 640; v += 256) {
      float s = red[v] + red[640 + v] + red[1280 + v] + red[1920 + v];
      Bp[(size_t)kc * (OUT_U * NH) + jt * 640 + v] = s;
    }
  } else {
    // ---- castX ----
    int idx = (blk - 768) * 256 + tid;
    const float4* src = (const float4*)X;
    float4 a = src[idx * 2];
    float4 b = src[idx * 2 + 1];
    f16x8 o;
    o[0] = (f16)a.x; o[1] = (f16)a.y; o[2] = (f16)a.z; o[3] = (f16)a.w;
    o[4] = (f16)b.x; o[5] = (f16)b.y; o[6] = (f16)b.z; o[7] = (f16)b.w;
    *((f16x8*)X16 + idx) = o;
  }
}

// ================= k_wnew: W_new^T (f16), B-partials reduced in =================
// 64x64 (i,j) tile. MLP weights in LDS (wave-uniform broadcast reads, conflict-free).
// JB=4 j-register-blocking: each W2 broadcast read feeds 4 FMAs. All indices static.
__global__ __launch_bounds__(256) void k_wnew(const float* __restrict__ W,
                                              const float* __restrict__ A,
                                              const float* __restrict__ Bp,
                                              const float* __restrict__ b1,
                                              const float* __restrict__ W2,
                                              const float* __restrict__ b2,
                                              const float* __restrict__ W3,
                                              const float* __restrict__ b3,
                                              f16* __restrict__ WnT) {
  __shared__ float Wt[64 * 65];
  __shared__ float As[64 * NH];
  __shared__ float Bs[64 * NH];
  __shared__ float W2s[NH * NH];
  __shared__ float b1s[NH], b2s[NH], w3s[NH];
  int tid = threadIdx.x;
  int i0 = blockIdx.x * 64, j0 = blockIdx.y * 64;
  // stage W tile transposed (read coalesced; write stride 65*4B -> conflict-free)
#pragma unroll
  for (int it = 0; it < 16; ++it) {
    int idx = it * 256 + tid;
    int r = idx >> 6, c = idx & 63;
    Wt[c * 65 + r] = W[(size_t)(i0 + r) * OUT_U + j0 + c];
  }
  for (int v = tid; v < 64 * NH; v += 256) {
    As[v] = A[(size_t)i0 * NH + v];
    float s = 0.f;
#pragma unroll
    for (int kc = 0; kc < 8; ++kc) s += Bp[(size_t)kc * (OUT_U * NH) + (size_t)j0 * NH + v];
    Bs[v] = s;
  }
  if (tid < NH * NH) W2s[tid] = W2[tid];
  if (tid < NH) { b1s[tid] = b1[tid]; b2s[tid] = b2[tid]; w3s[tid] = W3[tid]; }
  __syncthreads();

  int lane = tid & 63, w = tid >> 6;
  float b3v = b3[0];
  float ar[NH];
#pragma unroll
  for (int h = 0; h < NH; ++h) ar[h] = As[lane * NH + h] + b1s[h];

#pragma unroll
  for (int g = 0; g < 4; ++g) {
    int jb = w * 16 + g * 4;  // wave-uniform
    float h1[4][NH], s2[4][NH];
#pragma unroll
    for (int u = 0; u < 4; ++u)
#pragma unroll
      for (int p = 0; p < NH; ++p)
        h1[u][p] = fmaxf(ar[p] + Bs[(jb + u) * NH + p], 0.f);
#pragma unroll
    for (int u = 0; u < 4; ++u)
#pragma unroll
      for (int q = 0; q < NH; ++q) s2[u][q] = b2s[q];
#pragma unroll
    for (int p = 0; p < NH; ++p) {
#pragma unroll
      for (int q = 0; q < NH; ++q) {
        float wv2 = W2s[p * NH + q];  // broadcast
#pragma unroll
        for (int u = 0; u < 4; ++u) s2[u][q] = fmaf(h1[u][p], wv2, s2[u][q]);
      }
    }
#pragma unroll
    for (int u = 0; u < 4; ++u) {
      float d = b3v;
#pragma unroll
      for (int q = 0; q < NH; ++q) d = fmaf(fmaxf(s2[u][q], 0.f), w3s[q], d);
      float wn = Wt[(jb + u) * 65 + lane] + d;
      WnT[(size_t)(j0 + jb + u) * IN_U + i0 + lane] = (f16)wn;
    }
  }
}

// ================= k_gemm: logits = X16 @ WnT^T (128^2, dbuf prefetch, XCD swz) ==
__device__ __forceinline__ void gld_lds16(const void* g, void* l) {
  __builtin_amdgcn_global_load_lds((const __attribute__((address_space(1))) uint32_t*)g,
                                   (__attribute__((address_space(3))) uint32_t*)l, 16, 0, 0);
}

__global__ __launch_bounds__(256) void k_gemm(const f16* __restrict__ Am,
                                              const f16* __restrict__ Bt,
                                              float* __restrict__ C) {
  constexpr int K = IN_U;   // 2048
  constexpr int N = OUT_U;  // 2048
  constexpr int NKT = K / 32;  // 64
  __shared__ f16 Asl[2][128 * 32];
  __shared__ f16 Bsl[2][128 * 32];
  int tid = threadIdx.x;
  int lane = tid & 63;
  int w = tid >> 6;
  int wr = w >> 1, wc = w & 1;

  // T1: bijective XCD swizzle (512 blocks, 512%8==0)
  int orig = blockIdx.x;
  int swz = (orig & 7) * 64 + (orig >> 3);
  int bm = swz >> 4;   // 0..31 (M tiles)
  int bn = swz & 15;   // 0..15 (N tiles)

  int srow = w * 16 + (lane >> 2);
  int scol = (lane & 3) * 8;
  const f16* srcA0 = Am + (size_t)(bm * 128 + srow) * K + scol;
  const f16* srcA1 = srcA0 + (size_t)64 * K;
  const f16* srcB0 = Bt + (size_t)(bn * 128 + srow) * K + scol;
  const f16* srcB1 = srcB0 + (size_t)64 * K;

  f32x4 acc[4][4];
#pragma unroll
  for (int m = 0; m < 4; ++m)
#pragma unroll
    for (int n = 0; n < 4; ++n) acc[m][n] = (f32x4){0.f, 0.f, 0.f, 0.f};

  int rdA = (wr * 64 + (lane & 15)) * 32 + (lane >> 4) * 8;
  int rdB = (wc * 64 + (lane & 15)) * 32 + (lane >> 4) * 8;

  // prologue: stage tile 0 into buf 0
  gld_lds16(srcA0, &Asl[0][w * 512]);
  gld_lds16(srcA1, &Asl[0][2048 + w * 512]);
  gld_lds16(srcB0, &Bsl[0][w * 512]);
  gld_lds16(srcB1, &Bsl[0][2048 + w * 512]);
  srcA0 += 32; srcA1 += 32; srcB0 += 32; srcB1 += 32;
  __syncthreads();

  for (int kt = 0; kt < NKT; ++kt) {
    int cur = kt & 1;
    if (kt + 1 < NKT) {  // stage next tile into the other buffer (overlaps compute)
      gld_lds16(srcA0, &Asl[cur ^ 1][w * 512]);
      gld_lds16(srcA1, &Asl[cur ^ 1][2048 + w * 512]);
      gld_lds16(srcB0, &Bsl[cur ^ 1][w * 512]);
      gld_lds16(srcB1, &Bsl[cur ^ 1][2048 + w * 512]);
      srcA0 += 32; srcA1 += 32; srcB0 += 32; srcB1 += 32;
    }
    f16x8 af[4], bf[4];
#pragma unroll
    for (int m = 0; m < 4; ++m) af[m] = *(const f16x8*)(&Asl[cur][rdA + m * 16 * 32]);
#pragma unroll
    for (int n = 0; n < 4; ++n) bf[n] = *(const f16x8*)(&Bsl[cur][rdB + n * 16 * 32]);
#pragma unroll
    for (int m = 0; m < 4; ++m)
#pragma unroll
      for (int n = 0; n < 4; ++n)
        acc[m][n] = __builtin_amdgcn_mfma_f32_16x16x32_f16(af[m], bf[n], acc[m][n], 0, 0, 0);
    __syncthreads();  // drains vmcnt (stage of next) + lgkm; one barrier per K-step
  }

  // D layout: col = lane&15, row = (lane>>4)*4 + v  (m89/m91 verified)
  int r0 = bm * 128 + wr * 64 + (lane >> 4) * 4;
  int c0 = bn * 128 + wc * 64 + (lane & 15);
#pragma unroll
  for (int m = 0; m < 4; ++m)
#pragma unroll
    for (int n = 0; n < 4; ++n)
#pragma unroll
      for (int v = 0; v < 4; ++v)
        C[(size_t)(r0 + m * 16 + v) * N + c0 + n * 16] = acc[m][n][v];
}

// ================= k_softmax: row softmax in-place =================
__global__ __launch_bounds__(256) void k_softmax(float* __restrict__ L) {
  __shared__ float sred[4];
  int tid = threadIdx.x;
  int lane = tid & 63, w = tid >> 6;
  float4* Lr = (float4*)(L + (size_t)blockIdx.x * OUT_U);
  float4 v0 = Lr[tid];
  float4 v1 = Lr[tid + 256];
  float m = fmaxf(fmaxf(fmaxf(v0.x, v0.y), fmaxf(v0.z, v0.w)),
                  fmaxf(fmaxf(v1.x, v1.y), fmaxf(v1.z, v1.w)));
#pragma unroll
  for (int off = 32; off > 0; off >>= 1) m = fmaxf(m, __shfl_xor(m, off, 64));
  if (lane == 0) sred[w] = m;
  __syncthreads();
  m = fmaxf(fmaxf(sred[0], sred[1]), fmaxf(sred[2], sred[3]));
  __syncthreads();
  v0.x = __expf(v0.x - m); v0.y = __expf(v0.y - m);
  v0.z = __expf(v0.z - m); v0.w = __expf(v0.w - m);
  v1.x = __expf(v1.x - m); v1.y = __expf(v1.y - m);
  v1.z = __expf(v1.z - m); v1.w = __expf(v1.w - m);
  float s = v0.x + v0.y + v0.z + v0.w + v1.x + v1.y + v1.z + v1.w;
#pragma unroll
  for (int off = 32; off > 0; off >>= 1) s += __shfl_xor(s, off, 64);
  if (lane == 0) sred[w] = s;
  __syncthreads();
  s = sred[0] + sred[1] + sred[2] + sred[3];
  float inv = 1.f / s;
  v0.x *= inv; v0.y *= inv; v0.z *= inv; v0.w *= inv;
  v1.x *= inv; v1.y *= inv; v1.z *= inv; v1.w *= inv;
  Lr[tid] = v0;
  Lr[tid + 256] = v1;
}

extern "C" void kernel_launch(void* const* d_in, const int* in_sizes, int n_in,
                              void* d_out, int out_size, void* d_ws, size_t ws_size,
                              hipStream_t stream) {
  const float* X  = (const float*)d_in[0];
  const float* W  = (const float*)d_in[1];
  const float* W1 = (const float*)d_in[2];
  const float* b1 = (const float*)d_in[3];
  const float* W2 = (const float*)d_in[4];
  const float* b2 = (const float*)d_in[5];
  const float* W3 = (const float*)d_in[6];
  const float* b3 = (const float*)d_in[7];
  float* out = (float*)d_out;

  uint8_t* ws = (uint8_t*)d_ws;
  float* A   = (float*)ws;                      // 2048*10*4          = 81,920 B
  float* Bp  = (float*)(ws + 81920);            // 8*2048*10*4        = 655,360 B
  f16*   X16 = (f16*)(ws + 737280);             // 4096*2048*2        = 16,777,216 B
  f16*   WnT = (f16*)(ws + 737280 + 16777216);  // 2048*2048*2        = 8,388,608 B

  hipLaunchKernelGGL(k_prep, dim3(4864), dim3(256), 0, stream, W, W1, X, A, Bp, X16);
  hipLaunchKernelGGL(k_wnew, dim3(32, 32), dim3(256), 0, stream, W, A, Bp, b1, W2, b2, W3, b3, WnT);
  hipLaunchKernelGGL(k_gemm, dim3(512), dim3(256), 0, stream, X16, WnT, out);
  hipLaunchKernelGGL(k_softmax, dim3(4096), dim3(256), 0, stream, out);
}